// Round 1
// baseline (54.055 us; speedup 1.0000x reference)
//
#include <hip/hip_runtime.h>
#include <math.h>

// MixedFeatureEmbedder: out[b, f, :] for f even = x[b,f]*W_num[f/2,:] + b_num[f/2,:]
//                       for f odd  = emb_tables[f/2, clip(rint(nan_to_num(x[b,f])),0,99), :]
// Shapes: x (8192,64) f32, W_num/b_num (32,128) f32, emb_tables (32,100,128) f32,
// out (8192,64,128) f32.  Output = 256 MiB -> write-BW bound.

#define TOKEN_DIM 128
#define N_FEAT 64
#define CARD 100

// One 32-lane group per output row (128 floats); each lane writes one float4.
// Block = 256 threads = 8 rows/block.
__global__ __launch_bounds__(256) void mixed_embed_kernel(
    const float* __restrict__ x,
    const float* __restrict__ W_num,
    const float* __restrict__ b_num,
    const float* __restrict__ emb,
    float* __restrict__ out,
    int n_rows)
{
    const int row  = blockIdx.x * 8 + (threadIdx.x >> 5);
    const int lane = threadIdx.x & 31;
    if (row >= n_rows) return;

    const int f  = row & (N_FEAT - 1);   // feature index
    const int f2 = f >> 1;               // index into W_num/b_num or emb tables

    const float xv = x[row];             // x is [BATCH][64] contiguous; row = b*64+f

    float4 r;
    if ((f & 1) == 0) {
        // numeric feature: out = x * W + b
        const float4 w  = reinterpret_cast<const float4*>(W_num)[f2 * (TOKEN_DIM/4) + lane];
        const float4 bb = reinterpret_cast<const float4*>(b_num)[f2 * (TOKEN_DIM/4) + lane];
        r.x = fmaf(xv, w.x, bb.x);
        r.y = fmaf(xv, w.y, bb.y);
        r.z = fmaf(xv, w.z, bb.z);
        r.w = fmaf(xv, w.w, bb.w);
    } else {
        // categorical feature: embedding lookup
        float xc = isnan(xv) ? 0.0f : xv;
        float ridx = rintf(xc);                       // round half-to-even, matches jnp.round
        ridx = fminf(fmaxf(ridx, 0.0f), (float)(CARD - 1));
        const int idx = (int)ridx;
        r = reinterpret_cast<const float4*>(emb)[(f2 * CARD + idx) * (TOKEN_DIM/4) + lane];
    }

    reinterpret_cast<float4*>(out)[row * (TOKEN_DIM/4) + lane] = r;
}

extern "C" void kernel_launch(void* const* d_in, const int* in_sizes, int n_in,
                              void* d_out, int out_size, void* d_ws, size_t ws_size,
                              hipStream_t stream) {
    const float* x     = (const float*)d_in[0];
    const float* W_num = (const float*)d_in[1];
    const float* b_num = (const float*)d_in[2];
    const float* emb   = (const float*)d_in[3];
    float* out = (float*)d_out;

    const int batch  = in_sizes[0] / N_FEAT;      // 8192
    const int n_rows = batch * N_FEAT;            // 524288
    const int blocks = (n_rows + 7) / 8;          // 8 rows per 256-thread block

    mixed_embed_kernel<<<blocks, 256, 0, stream>>>(x, W_num, b_num, emb, out, n_rows);
}